// Round 6
// baseline (22.450 us; speedup 1.0000x reference)
//
#include <hip/hip_runtime.h>
#include <math.h>

#define NB 4
#define CC 128
#define HW 784        // 28*28
#define KK 64
#define DD 512
#define TD 4          // d-rows per block
#define BLK 832       // 13 waves; >= HW so each thread owns <=1 pixel

// Single fused kernel, one block per (n, 4-d-row group):
//   grid = 4*128 = 512 blocks -> 2 blocks/CU -> 26 waves/CU (vs 13 at TD=8),
//   doubling latency hiding; LDS ~15 KB so both blocks co-reside.
//   - thread t owns pixel p=t (t<784): streams x[n,:,p], accumulating the
//     4 conv dot-products AND the per-pixel sum-of-squares in one pass
//   - weights staged transposed in LDS, read as ONE broadcast ds_read_b128
//   - feat = rinv*dot + bias staged in LDS
//   - waves 0..3 each do one row's softmax-weighted mean over P=784
//   - vlad[n,k,d] is k-independent (softmax over the spatial axis is invariant
//     to the per-(k,d) centroid shift) -> broadcast write via LDS
__global__ __launch_bounds__(BLK) void netvlad_fused_kernel(
    const float* __restrict__ x, const float* __restrict__ w,
    const float* __restrict__ b, float* __restrict__ out)
{
    __shared__ float w_s[CC][TD];        // 2 KB, transposed: [c][j]
    __shared__ float feat_s[TD][HW];     // 12.5 KB
    __shared__ float g_s[TD];

    const int tid = threadIdx.x;
    const int n  = blockIdx.x >> 7;      // 128 d-groups per n
    const int d0 = (blockIdx.x & 127) * TD;
    const bool act = tid < HW;

    // stage the 4x128 weight tile transposed (one-time, 512 floats)
    for (int i = tid; i < CC * TD; i += BLK) {
        int c = i >> 2, j = i & 3;
        w_s[c][j] = w[(size_t)(d0 + j) * CC + c];
    }
    __syncthreads();

    if (act) {
        const float* xp = x + (size_t)n * CC * HW + tid;
        float acc[TD];
        #pragma unroll
        for (int j = 0; j < TD; ++j) acc[j] = 0.f;
        float sq = 0.f;

        // 8-deep unroll: 8 independent x loads in flight (ILP on L2 latency)
        #pragma unroll 8
        for (int c = 0; c < CC; ++c) {
            float xv = xp[(size_t)c * HW];            // coalesced dword
            float4 wv = *(const float4*)&w_s[c][0];   // uniform addr -> broadcast
            sq = fmaf(xv, xv, sq);
            acc[0] = fmaf(wv.x, xv, acc[0]);
            acc[1] = fmaf(wv.y, xv, acc[1]);
            acc[2] = fmaf(wv.z, xv, acc[2]);
            acc[3] = fmaf(wv.w, xv, acc[3]);
        }

        float r = 1.0f / fmaxf(sqrtf(sq), 1e-12f);
        #pragma unroll
        for (int j = 0; j < TD; ++j)
            feat_s[j][tid] = fmaf(acc[j], r, b[d0 + j]);
    }
    __syncthreads();

    // Per-row softmax-weighted mean over P=784; wave j (j<4) handles row j.
    const int lane = tid & 63;
    const int wave = tid >> 6;
    if (wave < TD) {
        const int j = wave;
        float m = -INFINITY;
        for (int p = lane; p < HW; p += 64) m = fmaxf(m, feat_s[j][p]);
        #pragma unroll
        for (int off = 32; off; off >>= 1) m = fmaxf(m, __shfl_xor(m, off, 64));
        float s = 0.f, ws = 0.f;
        for (int p = lane; p < HW; p += 64) {
            float f = feat_s[j][p];
            float e = __expf(f - m);
            s += e;
            ws = fmaf(e, f, ws);
        }
        #pragma unroll
        for (int off = 32; off; off >>= 1) {
            s  += __shfl_xor(s, off, 64);
            ws += __shfl_xor(ws, off, 64);
        }
        if (lane == 0) g_s[j] = ws / s;
    }
    __syncthreads();

    // Broadcast across k: block owns out[n, :, d0:d0+4]
    if (tid < KK * TD) {
        int k = tid >> 2, j = tid & 3;
        out[(size_t)n * KK * DD + (size_t)k * DD + d0 + j] = g_s[j];
    }
}

extern "C" void kernel_launch(void* const* d_in, const int* in_sizes, int n_in,
                              void* d_out, int out_size, void* d_ws, size_t ws_size,
                              hipStream_t stream) {
    const float* x = (const float*)d_in[0];   // (4,128,28,28)
    const float* w = (const float*)d_in[1];   // (512,128)
    const float* b = (const float*)d_in[2];   // (512,)
    // d_in[3] = centroids (64,512): provably unused — softmax over the spatial
    // axis is invariant to the per-(k,d) constant shift, so vlad[n,k,d] is
    // identical for all k.
    float* out = (float*)d_out;               // (4,64,512) fp32

    netvlad_fused_kernel<<<NB * (DD / TD), BLK, 0, stream>>>(x, w, b, out);
}

// Round 7
// 18.048 us; speedup vs baseline: 1.2439x; 1.2439x over previous
//
#include <hip/hip_runtime.h>
#include <math.h>

#define NB 4
#define CC 128
#define HW 784        // 28*28
#define KK 64
#define DD 512
#define TD 8          // d-rows per block
#define BLK 832       // 13 waves; >= HW so each thread owns <=1 pixel

// Single fused kernel, one block per (n, 8-d-row group), 13 waves for TLP.
// Key point this revision: the main loop has NO divergent guard, so the
// wave-uniform weight reads wb[j*CC+c] sit in uniform control flow and the
// compiler can scalarize them into s_load -> SGPRs (SMEM pipe). Inner loop is
// then 1 coalesced vector load + 9 VALU FMAs, with zero LDS traffic.
// Inactive lanes (tid>=784) clamp their pixel index and discard results.
//   - thread t owns pixel p: streams x[n,:,p], accumulating the 8 conv dots
//     AND the per-pixel sum-of-squares in one pass
//   - feat = rinv*dot + bias staged in LDS
//   - waves 0..7 each do one row's softmax-weighted mean over P=784
//   - vlad[n,k,d] is k-independent (softmax over the spatial axis is invariant
//     to the per-(k,d) centroid shift) -> broadcast write via LDS
__global__ __launch_bounds__(BLK) void netvlad_fused_kernel(
    const float* __restrict__ x, const float* __restrict__ w,
    const float* __restrict__ b, float* __restrict__ out)
{
    __shared__ float feat_s[TD][HW];     // 25 KB
    __shared__ float g_s[TD];

    const int tid = threadIdx.x;
    const int n  = blockIdx.x >> 6;      // 64 d-groups per n
    const int d0 = (blockIdx.x & 63) * TD;
    const bool act = tid < HW;
    const int p = act ? tid : (HW - 1);  // clamp: keeps loads in-bounds, no branch

    const float* xp = x + (size_t)n * CC * HW + p;
    const float* wb = w + (size_t)d0 * CC;    // uniform base, 8 rows of 128

    float acc[TD];
    #pragma unroll
    for (int j = 0; j < TD; ++j) acc[j] = 0.f;
    float sq = 0.f;

    // Uniform control flow: weight reads scalarize to s_load (SGPR operands),
    // x loads are coalesced dwords with 8 in flight per unroll chunk.
    #pragma unroll 8
    for (int c = 0; c < CC; ++c) {
        float xv = xp[(size_t)c * HW];
        sq = fmaf(xv, xv, sq);
        #pragma unroll
        for (int j = 0; j < TD; ++j) {
            acc[j] = fmaf(wb[j * CC + c], xv, acc[j]);   // wave-uniform -> SGPR
        }
    }

    if (act) {
        float r = 1.0f / fmaxf(sqrtf(sq), 1e-12f);
        #pragma unroll
        for (int j = 0; j < TD; ++j)
            feat_s[j][tid] = fmaf(acc[j], r, b[d0 + j]);  // b uniform too
    }
    __syncthreads();

    // Per-row softmax-weighted mean over P=784; wave j (j<8) handles row j.
    const int lane = tid & 63;
    const int wave = tid >> 6;
    if (wave < TD) {
        const int j = wave;
        float m = -INFINITY;
        for (int q = lane; q < HW; q += 64) m = fmaxf(m, feat_s[j][q]);
        #pragma unroll
        for (int off = 32; off; off >>= 1) m = fmaxf(m, __shfl_xor(m, off, 64));
        float s = 0.f, ws = 0.f;
        for (int q = lane; q < HW; q += 64) {
            float f = feat_s[j][q];
            float e = __expf(f - m);
            s += e;
            ws = fmaf(e, f, ws);
        }
        #pragma unroll
        for (int off = 32; off; off >>= 1) {
            s  += __shfl_xor(s, off, 64);
            ws += __shfl_xor(ws, off, 64);
        }
        if (lane == 0) g_s[j] = ws / s;
    }
    __syncthreads();

    // Broadcast across k with a coalesced write: block owns out[n, :, d0:d0+8]
    if (tid < KK * TD) {
        int k = tid >> 3, j = tid & 7;
        out[(size_t)n * KK * DD + (size_t)k * DD + d0 + j] = g_s[j];
    }
}

extern "C" void kernel_launch(void* const* d_in, const int* in_sizes, int n_in,
                              void* d_out, int out_size, void* d_ws, size_t ws_size,
                              hipStream_t stream) {
    const float* x = (const float*)d_in[0];   // (4,128,28,28)
    const float* w = (const float*)d_in[1];   // (512,128)
    const float* b = (const float*)d_in[2];   // (512,)
    // d_in[3] = centroids (64,512): provably unused — softmax over the spatial
    // axis is invariant to the per-(k,d) constant shift, so vlad[n,k,d] is
    // identical for all k.
    float* out = (float*)d_out;               // (4,64,512) fp32

    netvlad_fused_kernel<<<NB * (DD / TD), BLK, 0, stream>>>(x, w, b, out);
}